// Round 7
// baseline (1812.940 us; speedup 1.0000x reference)
//
#include <hip/hip_runtime.h>
#include <stdint.h>
#include <math.h>

#define N_ROWS 8192
#define N_TOK  8192
#define N_DIM  512
#define N_SAMP 10
#define GK     1536   // 3 * 512, bf16x2 split zones

typedef __attribute__((ext_vector_type(8))) short bf16x8_t;
typedef __attribute__((ext_vector_type(4))) float f32x4_t;

// ---------------- JAX threefry2x32 (exact) ----------------
__host__ __device__ __forceinline__ void tf2x32(uint32_t ks0, uint32_t ks1,
                                                uint32_t& x0, uint32_t& x1) {
  uint32_t ks2 = ks0 ^ ks1 ^ 0x1BD11BDAu;
  x0 += ks0; x1 += ks1;
#define TF_ROUND(r) { x0 += x1; x1 = (x1 << (r)) | (x1 >> (32 - (r))); x1 ^= x0; }
  TF_ROUND(13) TF_ROUND(15) TF_ROUND(26) TF_ROUND(6)
  x0 += ks1; x1 += ks2 + 1u;
  TF_ROUND(17) TF_ROUND(29) TF_ROUND(16) TF_ROUND(24)
  x0 += ks2; x1 += ks0 + 2u;
  TF_ROUND(13) TF_ROUND(15) TF_ROUND(26) TF_ROUND(6)
  x0 += ks0; x1 += ks1 + 3u;
  TF_ROUND(17) TF_ROUND(29) TF_ROUND(16) TF_ROUND(24)
  x0 += ks1; x1 += ks2 + 4u;
  TF_ROUND(13) TF_ROUND(15) TF_ROUND(26) TF_ROUND(6)
  x0 += ks2; x1 += ks0 + 5u;
#undef TF_ROUND
}

__device__ __forceinline__ unsigned short f2bf_rne(float f) {
  uint32_t u = __float_as_uint(f);
  uint32_t r = (u + 0x7fffu + ((u >> 16) & 1u)) >> 16;
  return (unsigned short)r;
}
__device__ __forceinline__ float bf2f(unsigned short h) {
  return __uint_as_float((uint32_t)h << 16);
}

__device__ __forceinline__ unsigned long long shfl_xor_u64(unsigned long long v, int off) {
  uint32_t lo = (uint32_t)v, hi = (uint32_t)(v >> 32);
  lo = (uint32_t)__shfl_xor((int)lo, off, 64);
  hi = (uint32_t)__shfl_xor((int)hi, off, 64);
  return ((unsigned long long)hi << 32) | lo;
}

// ---------------- row sum-of-squares ----------------
__global__ __launch_bounds__(256) void rownorm_kernel(const float* __restrict__ M,
                                                      float* __restrict__ out) {
  int lane = threadIdx.x & 63;
  int row = (int)((blockIdx.x * blockDim.x + threadIdx.x) >> 6);
  const float* p = M + (size_t)row * N_DIM;
  float acc = 0.f;
#pragma unroll
  for (int d = 0; d < N_DIM; d += 64) {
    float v = p[d + lane];
    acc = fmaf(v, v, acc);
  }
#pragma unroll
  for (int off = 32; off; off >>= 1) acc += __shfl_xor(acc, off, 64);
  if (lane == 0) out[row] = acc;
}

__global__ __launch_bounds__(256) void init_pack_kernel(unsigned long long* __restrict__ rpack) {
  int i = blockIdx.x * 256 + threadIdx.x;
  if (i < N_ROWS * N_SAMP) rpack[i] = 0xFFFFFFFFFFFFFFFFULL;
}

// ---------------- bf16x2 split ----------------
__global__ __launch_bounds__(256) void split_kernel(const float* __restrict__ src,
                                                    unsigned short* __restrict__ dst,
                                                    int mode) {
  int t = blockIdx.x * 256 + threadIdx.x;
  int row = t >> 7;
  int c = (t & 127) << 2;
  float4 v = *(const float4*)(src + (size_t)row * N_DIM + c);
  ushort4 hi, lo;
  hi.x = f2bf_rne(v.x); lo.x = f2bf_rne(v.x - bf2f(hi.x));
  hi.y = f2bf_rne(v.y); lo.y = f2bf_rne(v.y - bf2f(hi.y));
  hi.z = f2bf_rne(v.z); lo.z = f2bf_rne(v.z - bf2f(hi.z));
  hi.w = f2bf_rne(v.w); lo.w = f2bf_rne(v.w - bf2f(hi.w));
  unsigned short* base = dst + (size_t)row * GK;
  *(ushort4*)(base + c) = hi;
  if (mode == 0) {
    *(ushort4*)(base + 512 + c) = lo;
    *(ushort4*)(base + 1024 + c) = hi;
  } else {
    *(ushort4*)(base + 512 + c) = hi;
    *(ushort4*)(base + 1024 + c) = lo;
  }
}

// ---------------- FUSED: bf16 MFMA GEMM + gumbel sampling in epilogue ----------------
__device__ __forceinline__ void async_cp16(const void* g, void* l) {
  __builtin_amdgcn_global_load_lds((const __attribute__((address_space(1))) void*)g,
                                   (__attribute__((address_space(3))) void*)l, 16, 0, 0);
}

__global__ __launch_bounds__(256) void fused_gemm_sample_kernel(
    const unsigned short* __restrict__ A2, const unsigned short* __restrict__ B2,
    const float* __restrict__ xx, const float* __restrict__ ee,
    unsigned long long* __restrict__ rpack, uint32_t k0s, uint32_t k1s) {
  __shared__ __align__(16) unsigned short As[128 * 32];
  __shared__ __align__(16) unsigned short Bs[128 * 32];
  int tid = threadIdx.x;
  int w = tid >> 6, l = tid & 63;
  int row0 = blockIdx.y * 128;
  int col0 = blockIdx.x * 128;
  int wm = (w & 1) * 64, wn = (w >> 1) * 64;
  int quad = l >> 4, r15 = l & 15;

  f32x4_t acc[4][4];
#pragma unroll
  for (int i = 0; i < 4; ++i)
#pragma unroll
    for (int j = 0; j < 4; ++j) acc[i][j] = (f32x4_t){0.f, 0.f, 0.f, 0.f};

  int c0 = w * 64 + l;
  int c1 = c0 + 256;
  const size_t ga0 = (size_t)(row0 + (c0 >> 2)) * GK + (c0 & 3) * 8;
  const size_t ga1 = (size_t)(row0 + (c1 >> 2)) * GK + (c1 & 3) * 8;
  const size_t gb0 = (size_t)(col0 + (c0 >> 2)) * GK + (c0 & 3) * 8;
  const size_t gb1 = (size_t)(col0 + (c1 >> 2)) * GK + (c1 & 3) * 8;

  for (int k0 = 0; k0 < GK; k0 += 32) {
    async_cp16(A2 + ga0 + k0, As + c0 * 8);
    async_cp16(A2 + ga1 + k0, As + c1 * 8);
    async_cp16(B2 + gb0 + k0, Bs + c0 * 8);
    async_cp16(B2 + gb1 + k0, Bs + c1 * 8);
    __syncthreads();

    bf16x8_t af[4], bf[4];
#pragma unroll
    for (int i = 0; i < 4; ++i)
      af[i] = *(const bf16x8_t*)&As[(wm + i * 16 + r15) * 32 + quad * 8];
#pragma unroll
    for (int j = 0; j < 4; ++j)
      bf[j] = *(const bf16x8_t*)&Bs[(wn + j * 16 + r15) * 32 + quad * 8];
#pragma unroll
    for (int i = 0; i < 4; ++i)
#pragma unroll
      for (int j = 0; j < 4; ++j)
        acc[i][j] = __builtin_amdgcn_mfma_f32_16x16x32_bf16(af[i], bf[j], acc[i][j], 0, 0, 0);
    __syncthreads();
  }

  // ---- epilogue phase 1: acc -> E = expf(dist), in place (identical formula to r6) ----
  const float inv_nt = 1.f / 8192.f;
  float eev[4];
#pragma unroll
  for (int j = 0; j < 4; ++j) eev[j] = ee[col0 + wn + j * 16 + r15];
#pragma unroll
  for (int i = 0; i < 4; ++i) {
#pragma unroll
    for (int r = 0; r < 4; ++r) {
      float xxv = xx[row0 + wm + i * 16 + quad * 4 + r];
#pragma unroll
      for (int j = 0; j < 4; ++j)
        acc[i][j][r] = expf((xxv + eev[j] - 2.0f * acc[i][j][r]) * inv_nt);
    }
  }

  // ---- epilogue phase 2: 10 gumbel draws per element, packed argmin merge ----
  const float tiny = 1.1754943508222875e-38f;
  uint32_t kcol[4];
#pragma unroll
  for (int j = 0; j < 4; ++j) kcol[j] = (uint32_t)(col0 + wn + j * 16 + r15);
  int rbase = row0 + wm + quad * 4;

  for (int s = 0; s < N_SAMP; ++s) {
    uint32_t soff = (uint32_t)s * 8192u;
#pragma unroll
    for (int i = 0; i < 4; ++i) {
#pragma unroll
      for (int r = 0; r < 4; ++r) {
        uint32_t rowid = (uint32_t)(rbase + i * 16 + r);
        uint32_t cbase = rowid * 81920u + soff;
        unsigned long long b = 0xFFFFFFFFFFFFFFFFULL;
#pragma unroll
        for (int j = 0; j < 4; ++j) {
          uint32_t x0 = 0u, x1 = cbase + kcol[j];
          tf2x32(k0s, k1s, x0, x1);
          uint32_t bits = x0 ^ x1;
          float u = __uint_as_float(0x3f800000u | (bits >> 9)) - 1.0f;
          u = fmaxf(u, tiny);
          float wv = -logf(u) * acc[i][j][r];   // == r6 wv, bit-identical
          unsigned long long p =
              ((unsigned long long)__float_as_uint(wv) << 32) | kcol[j];
          b = (p < b) ? p : b;
        }
        // reduce across the 16-lane r15 group (same quad -> same rowid)
#pragma unroll
        for (int off = 1; off < 16; off <<= 1) {
          unsigned long long ob = shfl_xor_u64(b, off);
          b = (ob < b) ? ob : b;
        }
        if (r15 == 0) atomicMin(&rpack[(size_t)rowid * N_SAMP + s], b);
      }
    }
  }
}

// ---------------- fp32 NT GEMM (fallback) with E-epilogue ----------------
__global__ __launch_bounds__(256) void gemm_nt_kernel(const float* __restrict__ A,
                                                      const float* __restrict__ B,
                                                      const float* __restrict__ xx,
                                                      const float* __restrict__ ee,
                                                      float* __restrict__ E,
                                                      int ks, int KC) {
  __shared__ __align__(16) float Asf[32][68];
  __shared__ __align__(16) float Bsf[32][68];
  int tid = threadIdx.x;
  int row0 = blockIdx.y * 64;
  int colB0 = blockIdx.x * 64 + ks;
  int tx = tid & 15, ty = tid >> 4;
  float acc[4][4] = {};
  for (int d0 = 0; d0 < N_DIM; d0 += 32) {
#pragma unroll
    for (int r = 0; r < 2; ++r) {
      int c = tid + 256 * r;
      int m = c >> 3;
      int dv = (c & 7) << 2;
      const float4 va = *(const float4*)(A + (size_t)(row0 + m) * N_DIM + d0 + dv);
      Asf[dv + 0][m] = va.x; Asf[dv + 1][m] = va.y;
      Asf[dv + 2][m] = va.z; Asf[dv + 3][m] = va.w;
      const float4 vb = *(const float4*)(B + (size_t)(colB0 + m) * N_DIM + d0 + dv);
      Bsf[dv + 0][m] = vb.x; Bsf[dv + 1][m] = vb.y;
      Bsf[dv + 2][m] = vb.z; Bsf[dv + 3][m] = vb.w;
    }
    __syncthreads();
#pragma unroll
    for (int dd = 0; dd < 32; ++dd) {
      float4 a4 = *(const float4*)&Asf[dd][ty << 2];
      float4 b4 = *(const float4*)&Bsf[dd][tx << 2];
      float av[4] = {a4.x, a4.y, a4.z, a4.w};
      float bv[4] = {b4.x, b4.y, b4.z, b4.w};
#pragma unroll
      for (int i = 0; i < 4; ++i)
#pragma unroll
        for (int j = 0; j < 4; ++j)
          acc[i][j] = fmaf(av[i], bv[j], acc[i][j]);
    }
    __syncthreads();
  }
  const float inv_nt = 1.f / 8192.f;
  int colC0 = blockIdx.x * 64;
  float eev[4];
#pragma unroll
  for (int j = 0; j < 4; ++j) eev[j] = ee[ks + colC0 + (tx << 2) + j];
#pragma unroll
  for (int i = 0; i < 4; ++i) {
    int grow = row0 + (ty << 2) + i;
    float xxv = xx[grow];
    float4 v;
    v.x = expf((xxv + eev[0] - 2.0f * acc[i][0]) * inv_nt);
    v.y = expf((xxv + eev[1] - 2.0f * acc[i][1]) * inv_nt);
    v.z = expf((xxv + eev[2] - 2.0f * acc[i][2]) * inv_nt);
    v.w = expf((xxv + eev[3] - 2.0f * acc[i][3]) * inv_nt);
    *(float4*)(E + (size_t)grow * KC + colC0 + (tx << 2)) = v;
  }
}

// ---------------- strip sampler (fallback): E-read, packed atomic merge ----------------
__global__ __launch_bounds__(256) void sample_kernel(const float* __restrict__ E,
                                                     unsigned long long* __restrict__ rpack,
                                                     int ks, int KC,
                                                     uint32_t k0, uint32_t k1) {
  int lane = threadIdx.x & 63;
  int row = (int)((blockIdx.x * blockDim.x + threadIdx.x) >> 6);
  unsigned long long best[N_SAMP];
#pragma unroll
  for (int s = 0; s < N_SAMP; ++s) best[s] = 0xFFFFFFFFFFFFFFFFULL;
  const float tiny = 1.1754943508222875e-38f;
  uint32_t row_c = (uint32_t)row * 81920u;

  for (int kk = lane; kk < KC; kk += 64) {
    uint32_t k = (uint32_t)(ks + kk);
    float Ek = E[(size_t)row * KC + kk];
    uint32_t base_c = row_c + k;
#pragma unroll
    for (int s = 0; s < N_SAMP; ++s) {
      uint32_t x0 = 0u, x1 = base_c + (uint32_t)s * 8192u;
      tf2x32(k0, k1, x0, x1);
      uint32_t bits = x0 ^ x1;
      float u = __uint_as_float(0x3f800000u | (bits >> 9)) - 1.0f;
      u = fmaxf(u, tiny);
      float wv = -logf(u) * Ek;
      unsigned long long p = ((unsigned long long)__float_as_uint(wv) << 32) | k;
      if (p < best[s]) best[s] = p;
    }
  }
#pragma unroll
  for (int s = 0; s < N_SAMP; ++s) {
    unsigned long long b = best[s];
#pragma unroll
    for (int off = 32; off; off >>= 1) {
      unsigned long long ob = shfl_xor_u64(b, off);
      b = (ob < b) ? ob : b;
    }
    if (lane == 0) atomicMin(&rpack[(size_t)row * N_SAMP + s], b);
  }
}

// ---------------- G1: unpack rpack -> outs (float index) ----------------
__global__ __launch_bounds__(256) void unpack_kernel(const unsigned long long* __restrict__ rpack,
                                                     float* __restrict__ outs) {
  int i = blockIdx.x * 256 + threadIdx.x;
  if (i < N_ROWS * N_SAMP) outs[i] = (float)(uint32_t)(rpack[i] & 0xFFFFFFFFu);
}

// ---------------- G2: gather + mean + straight-through ----------------
__global__ __launch_bounds__(256) void gather_kernel(const float* __restrict__ emb,
                                                     const float* __restrict__ outs,
                                                     const float* __restrict__ x,
                                                     float* __restrict__ outq) {
  int lane = threadIdx.x & 63;
  int row = (int)((blockIdx.x * blockDim.x + threadIdx.x) >> 6);
  int idx[N_SAMP];
#pragma unroll
  for (int s = 0; s < N_SAMP; ++s) idx[s] = (int)outs[row * N_SAMP + s];
#pragma unroll
  for (int c = lane; c < N_DIM; c += 64) {
    float sum = 0.f;
#pragma unroll
    for (int s = 0; s < N_SAMP; ++s) sum += emb[(size_t)idx[s] * N_DIM + c];
    float qe = sum / 10.0f;
    float xv = x[(size_t)row * N_DIM + c];
    outq[(size_t)row * N_DIM + c] = xv + (qe - xv);
  }
}

extern "C" void kernel_launch(void* const* d_in, const int* in_sizes, int n_in,
                              void* d_out, int out_size, void* d_ws, size_t ws_size,
                              hipStream_t stream) {
  const float* x = (const float*)d_in[0];
  const float* emb = (const float*)d_in[1];
  float* out_q = (float*)d_out;
  float* out_s = out_q + (size_t)N_ROWS * N_DIM;

  const size_t pack_n = (size_t)N_ROWS * N_SAMP;                 // 81920 u64
  const size_t fixed_b = (N_ROWS + N_TOK) * 4 + pack_n * 8;      // xx+ee+rpack = 720896 B
  const size_t split_u = (size_t)N_ROWS * GK;

  uint32_t s0 = 0u, s1 = 1u;   // skey = fold_in(key(0), 1)
  tf2x32(0u, 0u, s0, s1);

  // ---- preferred: fused MFMA GEMM + sampling (needs fixed + 2 splits in ws) ----
  if (fixed_b + 2 * split_u * 2 <= ws_size) {
    float* xx = (float*)d_ws;
    float* ee = xx + N_ROWS;
    unsigned long long* rpack = (unsigned long long*)(ee + N_TOK);
    unsigned short* A2 = (unsigned short*)(rpack + pack_n);
    unsigned short* B2 = A2 + split_u;

    rownorm_kernel<<<2048, 256, 0, stream>>>(x, xx);
    rownorm_kernel<<<2048, 256, 0, stream>>>(emb, ee);
    init_pack_kernel<<<(int)((pack_n + 255) / 256), 256, 0, stream>>>(rpack);
    split_kernel<<<N_ROWS * 128 / 256, 256, 0, stream>>>(x, A2, 0);
    split_kernel<<<N_ROWS * 128 / 256, 256, 0, stream>>>(emb, B2, 1);

    fused_gemm_sample_kernel<<<dim3(64, 64), 256, 0, stream>>>(A2, B2, xx, ee, rpack, s0, s1);

    unpack_kernel<<<(int)((pack_n + 255) / 256), 256, 0, stream>>>(rpack, out_s);
    gather_kernel<<<2048, 256, 0, stream>>>(emb, out_s, x, out_q);
    return;
  }

  // ---- fallback: fp32 GEMM + E strip + strip sampler ----
  float *xx, *ee, *E;
  unsigned long long* rpack;
  int KC = 0;
  for (int c = 8192; c >= 64; c >>= 1) {
    if (fixed_b + (size_t)N_ROWS * c * 4 <= ws_size) { KC = c; break; }
  }
  if (KC) {
    xx = (float*)d_ws;
    ee = xx + N_ROWS;
    rpack = (unsigned long long*)(ee + N_TOK);
    E = (float*)(rpack + pack_n);
  } else if (fixed_b <= ws_size) {
    KC = 512;
    xx = (float*)d_ws;
    ee = xx + N_ROWS;
    rpack = (unsigned long long*)(ee + N_TOK);
    E = out_q;                      // outq dead until gather
  } else {
    // everything in d_out: E = outq[0 .. 8192*256), rpack/xx/ee after it
    KC = 256;
    E = out_q;
    rpack = (unsigned long long*)(out_q + (size_t)N_ROWS * 256);  // 8-byte aligned
    xx = (float*)(rpack + pack_n);
    ee = xx + N_ROWS;
    // used floats: 2097152 + 163840 + 16384 = 2277376 < 4194304 (inside outq) ✓
  }

  rownorm_kernel<<<2048, 256, 0, stream>>>(x, xx);
  rownorm_kernel<<<2048, 256, 0, stream>>>(emb, ee);
  init_pack_kernel<<<(int)((pack_n + 255) / 256), 256, 0, stream>>>(rpack);
  for (int ks = 0; ks < N_TOK; ks += KC) {
    gemm_nt_kernel<<<dim3(KC / 64, N_ROWS / 64), 256, 0, stream>>>(x, emb, xx, ee, E, ks, KC);
    sample_kernel<<<2048, 256, 0, stream>>>(E, rpack, ks, KC, s0, s1);
  }
  unpack_kernel<<<(int)((pack_n + 255) / 256), 256, 0, stream>>>(rpack, out_s);  // rpack dead after
  gather_kernel<<<2048, 256, 0, stream>>>(emb, out_s, x, out_q);
}